// Round 17
// baseline (611.400 us; speedup 1.0000x reference)
//
#include <hip/hip_runtime.h>

// WaveNet B=8 T=16384 RES=64 GATE=128 IN=256 OUT=256, 20 blocks, K=2.
// Fused 20-layer stack, flag-based neighbor sync, in-place o (L2-hot),
// halo mailboxes via agent-scope relaxed atomics (r9-r16-proven).
// R17 delta vs r16 (505us): __launch_bounds__(512,2) -> (512,4).
//   AMD semantics: 2nd arg = MIN WAVES PER SIMD (not blocks/CU). (512,2)
//   requested only 8 waves/CU = 1 block — r13-r16 never asked for 2-block
//   residency. (512,4) = 16 waves/CU = 2 blocks, reg cap 128/wave. r16's
//   acc2 halving (32->16 AGPR; accA/accG die before acc2 lives) brings the
//   body to ~112-128 total regs, so the cap should hold WITHOUT r12's
//   spill (r12's 144-reg body at cap 128 -> VGPR 64 + 440MB scratch).
//   Arithmetic unchanged -> absmax must stay 5.86e-3.
// d_out: o[0,16.8MB) | haloBuf @17MiB (100.5MB) | wpk @120MiB.
// d_ws : skip_bf16[0,16.8MB) | head weights bf16 | flags (19x512 u32).
// k_head reads ONLY d_ws -> no race with its full-d_out write (r2 lesson).

#define NB    20
#define RES   64
#define GATE  128
#define INC   256
#define OUTC  256
#define B_SZ  8
#define T_LEN 16384
#define HALO_COLS 1534     // sum of per-layer published columns

typedef short s16x4 __attribute__((ext_vector_type(4)));
typedef short s16x8 __attribute__((ext_vector_type(8)));
typedef float f32x4 __attribute__((ext_vector_type(4)));
typedef unsigned long long u64;

#define MFMA(a, b, c) __builtin_amdgcn_mfma_f32_16x16x32_bf16((a), (b), (c), 0, 0, 0)

// packed res-stack weight offsets (shorts) inside wpk
#define OFF_W0   0         // il_w   [64][512]      k = tap*256+ci
#define OFF_W1   32768     // rb_w1  [20][128][128] k = tap*64+ci
#define OFF_W2   360448    // rb_w2  [20][64][64]
#define PACK_N   442368

__device__ __forceinline__ short f2bf(float f) {
    union { float f; unsigned u; } v; v.f = f;
    unsigned r = v.u + 0x7FFFu + ((v.u >> 16) & 1u);
    return (short)(r >> 16);
}
__device__ __forceinline__ float bf2f(short s) {
    union { unsigned u; float f; } v;
    v.u = ((unsigned)(unsigned short)s) << 16;
    return v.f;
}
__device__ __forceinline__ unsigned cvt_pk_bf16(float lo, float hi) {
    unsigned r;
    asm("v_cvt_pk_bf16_f32 %0, %1, %2" : "=v"(r) : "v"(lo), "v"(hi));
    return r;
}
__device__ __forceinline__ float rcp_fast(float x) {
    float r; asm("v_rcp_f32 %0, %1" : "=v"(r) : "v"(x)); return r;
}
__device__ __forceinline__ float fast_sigmoid(float x) {
    return rcp_fast(1.0f + __expf(-x));
}
__device__ __forceinline__ float fast_tanh(float x) {
    x = fminf(fmaxf(x, -15.0f), 15.0f);
    float e = __expf(2.0f * x);
    return (e - 1.0f) * rcp_fast(e + 1.0f);
}
// halo slice s holds input halo for layer s: rightmost q_s=min(dil_s,256)
// cols of o_s per block. off(s) = sum_{j<s} q_j.
__device__ __forceinline__ int halo_off(int s) {
    int r = 0;
    if (s >= 10) { r = 767; s -= 10; }
    return r + ((s <= 8) ? ((1 << s) - 1) : 511);
}
__device__ __forceinline__ void poll_flag(unsigned* p) {
    long guard = 0;
    while (__hip_atomic_load(p, __ATOMIC_RELAXED, __HIP_MEMORY_SCOPE_AGENT) == 0u) {
        __builtin_amdgcn_s_sleep(1);
        if (++guard > 20000000L) break;   // anti-hang insurance
    }
}

// ---------------- res-stack weight pack ------------------------------------
__global__ __launch_bounds__(256) void k_pack(
    const float* __restrict__ il_w, const float* __restrict__ w1,
    const float* __restrict__ w2, short* __restrict__ dst)
{
    for (int idx = blockIdx.x * 256 + threadIdx.x; idx < PACK_N; idx += 512 * 256) {
        float v;
        if (idx < OFF_W1) {
            int m = idx >> 9, k = idx & 511, tap = k >> 8, ci = k & 255;
            v = il_w[(m * 256 + ci) * 2 + tap];
        } else if (idx < OFF_W2) {
            int j = idx - OFF_W1;
            int L = j >> 14, r = j & 16383;
            int m = r >> 7, k = r & 127, tap = k >> 6, ci = k & 63;
            v = w1[L * 16384 + (m * 64 + ci) * 2 + tap];
        } else {
            v = w2[idx - OFF_W2];
        }
        dst[idx] = f2bf(v);
    }
}

// ---------------- head weight pack -> d_ws ---------------------------------
__global__ __launch_bounds__(256) void k_packh(
    const float* __restrict__ w1, const float* __restrict__ w2,
    short* __restrict__ dst)
{
    int idx = blockIdx.x * 256 + threadIdx.x;     // grid 320 -> 81920
    if (idx < 81920) dst[idx] = f2bf(idx < 16384 ? w1[idx] : w2[idx - 16384]);
}

// ---------------- zero the halo flags (19*512 u32) -------------------------
__global__ __launch_bounds__(256) void k_zeroflags(unsigned* __restrict__ p) {
    int i = blockIdx.x * 256 + threadIdx.x;       // grid 38 -> 9728
    if (i < 19 * 512) p[i] = 0u;
}

// ---------------- input layer: o[b][t][64] = conv(x, d=1); publish slice0 --
__global__ __launch_bounds__(256, 4) void k_in(
    const float* __restrict__ x, const short* __restrict__ w0p,
    const float* __restrict__ bias, short* __restrict__ o,
    short* __restrict__ haloS)
{
    __shared__ short Xs[129][132];
    const int t0 = blockIdx.x * 128;
    const int b  = blockIdx.y;
    const int tid = threadIdx.x;
    const int w = tid >> 6, ln = tid & 63, tl = ln & 15, g = ln >> 4;
    const int tw = w * 32;

    f32x4 acc[4][2];
#pragma unroll
    for (int mt = 0; mt < 4; ++mt) {
        f32x4 bv = *(const f32x4*)(bias + mt * 16 + g * 4);
        acc[mt][0] = bv; acc[mt][1] = bv;
    }

    for (int c = 0; c < 2; ++c) {
        __syncthreads();
        for (int idx = tid; idx < 129 * 32; idx += 256) {
            int r = idx >> 5, c4 = (idx & 31) * 4;
            int tg = t0 - 1 + r;
            f32x4 v = (f32x4)0.0f;
            if (tg >= 0)
                v = *(const f32x4*)(x + ((size_t)b * T_LEN + tg) * INC + c * 128 + c4);
            s16x4 sv;
#pragma unroll
            for (int j = 0; j < 4; ++j) sv[j] = f2bf(v[j]);
            *(s16x4*)&Xs[r][c4] = sv;
        }
        __syncthreads();
#pragma unroll
        for (int ks = 0; ks < 8; ++ks) {
            int tap = ks >> 2;
            int ci  = (ks & 3) * 32 + g * 8;
            s16x8 bfr[2];
#pragma unroll
            for (int nf = 0; nf < 2; ++nf) {
                int row = tw + nf * 16 + tl + tap;
                s16x4 lo = *(const s16x4*)&Xs[row][ci];
                s16x4 hi = *(const s16x4*)&Xs[row][ci + 4];
                bfr[nf] = __builtin_shufflevector(lo, hi, 0, 1, 2, 3, 4, 5, 6, 7);
            }
#pragma unroll
            for (int mt = 0; mt < 4; ++mt) {
                const s16x8 a = *(const s16x8*)(
                    w0p + (size_t)(mt * 16 + tl) * 512 + tap * 256 + c * 128 + (ks & 3) * 32 + g * 8);
                acc[mt][0] = MFMA(a, bfr[0], acc[mt][0]);
                acc[mt][1] = MFMA(a, bfr[1], acc[mt][1]);
            }
        }
    }
#pragma unroll
    for (int mt = 0; mt < 4; ++mt)
#pragma unroll
        for (int nf = 0; nf < 2; ++nf) {
            int t = t0 + tw + nf * 16 + tl;
            s16x4 ov;
#pragma unroll
            for (int r = 0; r < 4; ++r) ov[r] = f2bf(acc[mt][nf][r]);
            *(s16x4*)(o + ((size_t)b * T_LEN + t) * RES + mt * 16 + g * 4) = ov;
            // publish layer-0 halo: col 255 of each 256-tile (q_0 = 1)
            if ((blockIdx.x & 1) && w == 3 && nf == 1 && tl == 15) {
                size_t hb = ((size_t)(b * 64 + (blockIdx.x >> 1)) * HALO_COLS) * 64;
                *(s16x4*)(haloS + hb + mt * 16 + g * 4) = ov;
            }
        }
}

// ---------------- fused residual stack (per-wave poll pipeline, 8 waves) ---
__global__ __launch_bounds__(512, 4) void k_fused(
    short* __restrict__ o,
    const short* __restrict__ wpk,
    const float* __restrict__ b1all, const float* __restrict__ b2all,
    short* __restrict__ skip_out,
    u64* __restrict__ halo, unsigned* __restrict__ flags)
{
    __shared__ short W1s[16384];    // [128][128] swizzled, 32 KB
    __shared__ short W2s[4096];     // [64][64]   swizzled,  8 KB
    __shared__ short Zs[256][68];   // z tile [t][ch], per-wave private rows
    const int raw = blockIdx.x;
    const int bx  = ((raw & 7) << 3) | ((raw >> 3) & 7);
    const int by  = raw >> 6;
    const int t0 = bx * 256;
    const int tid = threadIdx.x;
    const int w = tid >> 6, ln = tid & 63, tl = ln & 15, g = ln >> 4;
    const int tw = w * 32;          // 8 waves x 32 t
    const int xm = (tl & 7) << 4;
    const size_t ob = (size_t)by * T_LEN * RES;
    const int flatblk = by * 64 + bx;

    f32x4 skip[4][2];
#pragma unroll
    for (int mt = 0; mt < 4; ++mt)
#pragma unroll
        for (int nf = 0; nf < 2; ++nf) skip[mt][nf] = (f32x4)0.0f;

    for (int s = 0; s < NB; ++s) {
        const int dil = 1 << (s % 10);
        const int q   = (dil < 256) ? dil : 256;
        const int hoff = halo_off(s);
        const short* w1p = wpk + OFF_W1 + s * 16384;
        const short* w2p = wpk + OFF_W2 + s * 4096;
        const float* b1  = b1all + s * GATE;
        const float* b2  = b2all + s * RES;

        // ---- 1. stage weights -> LDS (shared by all 8 waves)
        for (int gi = tid; gi < 2560; gi += 512) {
            if (gi < 2048) {
                int m = gi >> 4, c = gi & 15;
                s16x8 v = *(const s16x8*)(w1p + m * 128 + c * 8);
                *(s16x8*)((char*)W1s + ((m * 256 + c * 16) ^ ((m & 7) << 4))) = v;
            } else {
                int g2 = gi - 2048;
                int m = g2 >> 3, c = g2 & 7;
                s16x8 v = *(const s16x8*)(w2p + m * 64 + c * 8);
                *(s16x8*)((char*)W2s + ((m * 128 + c * 16) ^ ((m & 7) << 4))) = v;
            }
        }

        // ---- 2. own-region B-frag loads (center taps + interior left taps)
        s16x8 bfr[2][4];
#pragma unroll
        for (int nf = 0; nf < 2; ++nf) {
            int t = t0 + tw + nf * 16 + tl;
#pragma unroll
            for (int ks = 0; ks < 2; ++ks) {
                int ci = ks * 32 + g * 8;
                int c = t - dil;
                s16x8 bf = (s16x8)0;
                if (c >= t0) bf = *(const s16x8*)(o + ob + (size_t)c * RES + ci);
                bfr[nf][ks] = bf;
            }
            bfr[nf][2] = *(const s16x8*)(o + ob + (size_t)t * RES + g * 8);
            bfr[nf][3] = *(const s16x8*)(o + ob + (size_t)t * RES + 32 + g * 8);
        }

        // ---- 3. barrier: staging visible + separates o reads (above) from
        //         o writes (epilogue below). Does NOT wait on any poll.
        __syncthreads();

        // ---- 4. per-wave poll: only waves whose left taps cross t0.
        if (s >= 1) {
            if (dil == 512) {
                if (bx >= 2 && ln == 0)
                    poll_flag(flags + (s - 1) * 512 + flatblk - 2);
            } else if (bx >= 1 && tw < dil) {
                if (ln == 0)
                    poll_flag(flags + (s - 1) * 512 + flatblk - 1);
            }
        }

        // ---- 5. boundary halo loads (u64 coherence-point reads)
#pragma unroll
        for (int nf = 0; nf < 2; ++nf) {
            int t = t0 + tw + nf * 16 + tl;
#pragma unroll
            for (int ks = 0; ks < 2; ++ks) {
                int c = t - dil;
                if (c < t0 && c >= 0) {
                    int ci = ks * 32 + g * 8;
                    int bxp = c >> 8;
                    int loc = (c & 255) - (256 - q);
                    const u64* hp = halo +
                        ((size_t)(by * 64 + bxp) * HALO_COLS + hoff + loc) * 16 + (ci >> 2);
                    union { u64 u[2]; s16x8 v; } un;
                    un.u[0] = __hip_atomic_load(hp + 0, __ATOMIC_RELAXED, __HIP_MEMORY_SCOPE_AGENT);
                    un.u[1] = __hip_atomic_load(hp + 1, __ATOMIC_RELAXED, __HIP_MEMORY_SCOPE_AGENT);
                    bfr[nf][ks] = un.v;
                }
            }
        }

        // ---- GEMM1 (gate conv) + gating
#pragma unroll
        for (int mp = 0; mp < 4; ++mp) {
            f32x4 accA[2], accG[2];
            f32x4 bA = *(const f32x4*)(b1 + mp * 16 + g * 4);
            f32x4 bG = *(const f32x4*)(b1 + 64 + mp * 16 + g * 4);
#pragma unroll
            for (int nf = 0; nf < 2; ++nf) { accA[nf] = bA; accG[nf] = bG; }
#pragma unroll
            for (int ks = 0; ks < 4; ++ks) {
                const s16x8 aA = *(const s16x8*)((const char*)W1s +
                    (((mp * 16 + tl) * 256 + ks * 64 + g * 16) ^ xm));
                const s16x8 aG = *(const s16x8*)((const char*)W1s +
                    ((((mp + 4) * 16 + tl) * 256 + ks * 64 + g * 16) ^ xm));
#pragma unroll
                for (int nf = 0; nf < 2; ++nf) {
                    accA[nf] = MFMA(aA, bfr[nf][ks], accA[nf]);
                    accG[nf] = MFMA(aG, bfr[nf][ks], accG[nf]);
                }
            }
#pragma unroll
            for (int nf = 0; nf < 2; ++nf) {
                float z0 = fast_tanh(accA[nf][0]) * fast_sigmoid(accG[nf][0]);
                float z1 = fast_tanh(accA[nf][1]) * fast_sigmoid(accG[nf][1]);
                float z2 = fast_tanh(accA[nf][2]) * fast_sigmoid(accG[nf][2]);
                float z3 = fast_tanh(accA[nf][3]) * fast_sigmoid(accG[nf][3]);
                unsigned* zp = (unsigned*)&Zs[tw + nf * 16 + tl][mp * 16 + g * 4];
                zp[0] = cvt_pk_bf16(z0, z1);
                zp[1] = cvt_pk_bf16(z2, z3);
            }
        }

        // ---- GEMM2 + epilogue in TWO mt-halves (acc2: 16 AGPRs)
        const int dn  = (s < NB - 1) ? (1 << ((s + 1) % 10)) : 0;
        const int qn  = (dn < 256) ? dn : 256;
        const int hoffn = (s < NB - 1) ? halo_off(s + 1) : 0;
#pragma unroll
        for (int mh = 0; mh < 2; ++mh) {
            f32x4 acc2[2][2];
#pragma unroll
            for (int m2 = 0; m2 < 2; ++m2) {
                f32x4 bv = *(const f32x4*)(b2 + (mh * 2 + m2) * 16 + g * 4);
#pragma unroll
                for (int nf = 0; nf < 2; ++nf) acc2[m2][nf] = bv;
            }
#pragma unroll
            for (int ks = 0; ks < 2; ++ks) {
                s16x8 bz[2];
#pragma unroll
                for (int nf = 0; nf < 2; ++nf) {
                    s16x4 lo = *(const s16x4*)&Zs[tw + nf * 16 + tl][ks * 32 + g * 8];
                    s16x4 hi = *(const s16x4*)&Zs[tw + nf * 16 + tl][ks * 32 + g * 8 + 4];
                    bz[nf] = __builtin_shufflevector(lo, hi, 0, 1, 2, 3, 4, 5, 6, 7);
                }
#pragma unroll
                for (int m2 = 0; m2 < 2; ++m2) {
                    const int mt = mh * 2 + m2;
                    const s16x8 a2 = *(const s16x8*)((const char*)W2s +
                        (((mt * 16 + tl) * 128 + ks * 64 + g * 16) ^ xm));
#pragma unroll
                    for (int nf = 0; nf < 2; ++nf)
                        acc2[m2][nf] = MFMA(a2, bz[nf], acc2[m2][nf]);
                }
            }
            // epilogue for this half: skip += s; o += s; publish halo
#pragma unroll
            for (int m2 = 0; m2 < 2; ++m2) {
                const int mt = mh * 2 + m2;
#pragma unroll
                for (int nf = 0; nf < 2; ++nf) {
#pragma unroll
                    for (int r = 0; r < 4; ++r) skip[mt][nf][r] += acc2[m2][nf][r];
                    if (s < NB - 1) {
                        int t_local = tw + nf * 16 + tl;
                        size_t base = ob + (size_t)(t0 + t_local) * RES + mt * 16 + g * 4;
                        s16x4 ov = *(const s16x4*)(o + base);
                        float f0 = bf2f(ov[0]) + acc2[m2][nf][0];
                        float f1 = bf2f(ov[1]) + acc2[m2][nf][1];
                        float f2 = bf2f(ov[2]) + acc2[m2][nf][2];
                        float f3 = bf2f(ov[3]) + acc2[m2][nf][3];
                        union { unsigned u[2]; s16x4 v; u64 uu; } un;
                        un.u[0] = cvt_pk_bf16(f0, f1);
                        un.u[1] = cvt_pk_bf16(f2, f3);
                        *(s16x4*)(o + base) = un.v;
                        if (t_local >= 256 - qn) {
                            int loc = t_local - (256 - qn);
                            u64* hp = halo +
                                ((size_t)flatblk * HALO_COLS + hoffn + loc) * 16 + mt * 4 + g;
                            __hip_atomic_store(hp, un.uu, __ATOMIC_RELAXED,
                                               __HIP_MEMORY_SCOPE_AGENT);
                        }
                    }
                }
            }
        }

        if (s < NB - 1) {
            asm volatile("s_waitcnt vmcnt(0)" ::: "memory");  // publish done
            __syncthreads();              // all waves drained
            if (tid == 0)
                __hip_atomic_store(flags + s * 512 + flatblk, 1u,
                                   __ATOMIC_RELAXED, __HIP_MEMORY_SCOPE_AGENT);
        }
    }

    // write skip (bf16) to d_ws — own tile only
#pragma unroll
    for (int mt = 0; mt < 4; ++mt)
#pragma unroll
        for (int nf = 0; nf < 2; ++nf) {
            int t = t0 + tw + nf * 16 + tl;
            unsigned* sp = (unsigned*)(skip_out + ob + (size_t)t * RES + mt * 16 + g * 4);
            sp[0] = cvt_pk_bf16(skip[mt][nf][0], skip[mt][nf][1]);
            sp[1] = cvt_pk_bf16(skip[mt][nf][2], skip[mt][nf][3]);
        }
}

// ---------------- output head (reads d_ws only) ----------------------------
__global__ __launch_bounds__(256, 4) void k_head(
    const short* __restrict__ skip,
    const short* __restrict__ w1p, const short* __restrict__ w2p,
    const float* __restrict__ b1h, const float* __restrict__ b2h,
    float* __restrict__ out)
{
    __shared__ short T1[64][260];
    const int t0 = blockIdx.x * 64;
    const int b  = blockIdx.y;
    const int tid = threadIdx.x;
    const int w = tid >> 6, ln = tid & 63, tl = ln & 15, g = ln >> 4;
    const int m0 = w * 64;

    f32x4 acc1[4][4];
#pragma unroll
    for (int mt = 0; mt < 4; ++mt) {
        f32x4 bv = *(const f32x4*)(b1h + m0 + mt * 16 + g * 4);
#pragma unroll
        for (int nf = 0; nf < 4; ++nf) acc1[mt][nf] = bv;
    }
#pragma unroll
    for (int ks = 0; ks < 2; ++ks) {
        s16x8 bs[4];
#pragma unroll
        for (int nf = 0; nf < 4; ++nf) {
            int t = t0 + nf * 16 + tl;
            s16x8 sv = *(const s16x8*)(skip + ((size_t)b * T_LEN + t) * RES + ks * 32 + g * 8);
            s16x8 v;
#pragma unroll
            for (int j = 0; j < 8; ++j)
                v[j] = (short)(((unsigned short)sv[j] & 0x8000u) ? 0 : sv[j]);  // relu(bf16)
            bs[nf] = v;
        }
#pragma unroll
        for (int mt = 0; mt < 4; ++mt) {
            const s16x8 a = *(const s16x8*)(w1p + (size_t)(m0 + mt * 16 + tl) * 64 + ks * 32 + g * 8);
#pragma unroll
            for (int nf = 0; nf < 4; ++nf) acc1[mt][nf] = MFMA(a, bs[nf], acc1[mt][nf]);
        }
    }
#pragma unroll
    for (int mt = 0; mt < 4; ++mt)
#pragma unroll
        for (int nf = 0; nf < 4; ++nf) {
            int tloc = nf * 16 + tl;
            s16x4 zv;
#pragma unroll
            for (int r = 0; r < 4; ++r) zv[r] = f2bf(fmaxf(acc1[mt][nf][r], 0.0f));
            *(s16x4*)&T1[tloc][m0 + mt * 16 + g * 4] = zv;
        }
    __syncthreads();

    f32x4 acc2[4][4];
#pragma unroll
    for (int mt = 0; mt < 4; ++mt) {
        f32x4 bv = *(const f32x4*)(b2h + m0 + mt * 16 + g * 4);
#pragma unroll
        for (int nf = 0; nf < 4; ++nf) acc2[mt][nf] = bv;
    }
#pragma unroll
    for (int ks = 0; ks < 8; ++ks) {
        s16x8 bz[4];
#pragma unroll
        for (int nf = 0; nf < 4; ++nf) {
            s16x4 lo = *(const s16x4*)&T1[nf * 16 + tl][ks * 32 + g * 8];
            s16x4 hi = *(const s16x4*)&T1[nf * 16 + tl][ks * 32 + g * 8 + 4];
            bz[nf] = __builtin_shufflevector(lo, hi, 0, 1, 2, 3, 4, 5, 6, 7);
        }
#pragma unroll
        for (int mt = 0; mt < 4; ++mt) {
            const s16x8 a = *(const s16x8*)(w2p + (size_t)(m0 + mt * 16 + tl) * 256 + ks * 32 + g * 8);
#pragma unroll
            for (int nf = 0; nf < 4; ++nf) acc2[mt][nf] = MFMA(a, bz[nf], acc2[mt][nf]);
        }
    }
#pragma unroll
    for (int mt = 0; mt < 4; ++mt)
#pragma unroll
        for (int nf = 0; nf < 4; ++nf) {
            int t = t0 + nf * 16 + tl;
#pragma unroll
            for (int r = 0; r < 4; ++r) {
                int ch = m0 + mt * 16 + g * 4 + r;
                out[((size_t)b * OUTC + ch) * T_LEN + t] = acc2[mt][nf][r];
            }
        }
}

extern "C" void kernel_launch(void* const* d_in, const int* in_sizes, int n_in,
                              void* d_out, int out_size, void* d_ws, size_t ws_size,
                              hipStream_t stream)
{
    const float* x     = (const float*)d_in[0];
    const float* il_w  = (const float*)d_in[1];
    const float* il_b  = (const float*)d_in[2];
    const float* rb_w1 = (const float*)d_in[3];
    const float* rb_b1 = (const float*)d_in[4];
    const float* rb_w2 = (const float*)d_in[5];
    const float* rb_b2 = (const float*)d_in[6];
    const float* ol_w1 = (const float*)d_in[7];
    const float* ol_b1 = (const float*)d_in[8];
    const float* ol_w2 = (const float*)d_in[9];
    const float* ol_b2 = (const float*)d_in[10];

    const size_t planeS = (size_t)B_SZ * T_LEN * RES;    // 8,388,608 shorts
    char*  outc = (char*)d_out;
    short* o    = (short*)outc;                          // [0, 16.78 MB) in-place o
    u64*   halo = (u64*)(outc + (17u << 20));            // 100.5 MB halo mailboxes
    short* wpk  = (short*)(outc + (120u << 20));         // packed res weights
    float* out  = (float*)d_out;

    short*    skipw = (short*)d_ws;                      // [0, 16.78 MB) bf16 skip
    short*    hw    = skipw + planeS;                    // +160 KB head weights
    unsigned* flags = (unsigned*)(hw + 81920);           // 19*512 u32

    k_pack<<<dim3(512), dim3(256), 0, stream>>>(il_w, rb_w1, rb_w2, wpk);
    k_packh<<<dim3(320), dim3(256), 0, stream>>>(ol_w1, ol_w2, hw);
    k_zeroflags<<<dim3(38), dim3(256), 0, stream>>>(flags);
    k_in<<<dim3(T_LEN / 128, B_SZ), dim3(256), 0, stream>>>(x, wpk + OFF_W0, il_b, o,
                                                            (short*)halo);

    k_fused<<<dim3(512), dim3(512), 0, stream>>>(
        o, wpk, rb_b1, rb_b2, skipw, halo, flags);

    k_head<<<dim3(T_LEN / 64, B_SZ), dim3(256), 0, stream>>>(
        skipw, hw, hw + 16384, ol_b1, ol_b2, out);
}

// Round 18
// 521.730 us; speedup vs baseline: 1.1719x; 1.1719x over previous
//
#include <hip/hip_runtime.h>

// WaveNet B=8 T=16384 RES=64 GATE=128 IN=256 OUT=256, 20 blocks, K=2.
// Fused 20-layer stack, flag-based neighbor sync, in-place o (L2-hot),
// halo mailboxes via agent-scope relaxed atomics (r9-r17-proven).
// R18 delta vs r17: 16t PER THREAD (1024-thr blocks, 16 waves x 16t,
//   tile stays 256t). Why: at any >=4-waves/SIMD reg cap (128) the
//   compiler splits the unified file 64 arch / 64 accum; the old body
//   needed ~96 arch VGPRs (skip 32 + bfr 32) -> spill (r12/r17, 543us).
//   Halving per-thread t-coverage halves skip+bfr to 16+16 -> ~60 arch,
//   fits the 64-arch half. launch_bounds(1024,4) = 4 waves/SIMD = 16
//   waves/CU at 1 block/CU -> 46% occupancy, NO spill (vs r13-17's 23.6%).
//   Grid 512 > 256 CUs: identity 2D grid (x-fastest) => producers have
//   lower dispatch IDs; chains drain by-0..3 then by-4..7. All halo/flag
//   formulas unchanged (tile 256). Arithmetic bit-identical (absmax 5.86e-3).
// d_out: o[0,16.8MB) | haloBuf @17MiB (100.5MB) | wpk @120MiB.
// d_ws : skip_bf16[0,16.8MB) | head weights bf16 | flags (19x512 u32).
// k_head reads ONLY d_ws -> no race with its full-d_out write (r2 lesson).

#define NB    20
#define RES   64
#define GATE  128
#define INC   256
#define OUTC  256
#define B_SZ  8
#define T_LEN 16384
#define HALO_COLS 1534     // sum of per-layer published columns

typedef short s16x4 __attribute__((ext_vector_type(4)));
typedef short s16x8 __attribute__((ext_vector_type(8)));
typedef float f32x4 __attribute__((ext_vector_type(4)));
typedef unsigned long long u64;

#define MFMA(a, b, c) __builtin_amdgcn_mfma_f32_16x16x32_bf16((a), (b), (c), 0, 0, 0)

// packed res-stack weight offsets (shorts) inside wpk
#define OFF_W0   0         // il_w   [64][512]      k = tap*256+ci
#define OFF_W1   32768     // rb_w1  [20][128][128] k = tap*64+ci
#define OFF_W2   360448    // rb_w2  [20][64][64]
#define PACK_N   442368

__device__ __forceinline__ short f2bf(float f) {
    union { float f; unsigned u; } v; v.f = f;
    unsigned r = v.u + 0x7FFFu + ((v.u >> 16) & 1u);
    return (short)(r >> 16);
}
__device__ __forceinline__ float bf2f(short s) {
    union { unsigned u; float f; } v;
    v.u = ((unsigned)(unsigned short)s) << 16;
    return v.f;
}
__device__ __forceinline__ unsigned cvt_pk_bf16(float lo, float hi) {
    unsigned r;
    asm("v_cvt_pk_bf16_f32 %0, %1, %2" : "=v"(r) : "v"(lo), "v"(hi));
    return r;
}
__device__ __forceinline__ float rcp_fast(float x) {
    float r; asm("v_rcp_f32 %0, %1" : "=v"(r) : "v"(x)); return r;
}
__device__ __forceinline__ float fast_sigmoid(float x) {
    return rcp_fast(1.0f + __expf(-x));
}
__device__ __forceinline__ float fast_tanh(float x) {
    x = fminf(fmaxf(x, -15.0f), 15.0f);
    float e = __expf(2.0f * x);
    return (e - 1.0f) * rcp_fast(e + 1.0f);
}
// halo slice s holds input halo for layer s: rightmost q_s=min(dil_s,256)
// cols of o_s per block. off(s) = sum_{j<s} q_j.
__device__ __forceinline__ int halo_off(int s) {
    int r = 0;
    if (s >= 10) { r = 767; s -= 10; }
    return r + ((s <= 8) ? ((1 << s) - 1) : 511);
}
__device__ __forceinline__ void poll_flag(unsigned* p) {
    long guard = 0;
    while (__hip_atomic_load(p, __ATOMIC_RELAXED, __HIP_MEMORY_SCOPE_AGENT) == 0u) {
        __builtin_amdgcn_s_sleep(1);
        if (++guard > 20000000L) break;   // anti-hang insurance
    }
}

// ---------------- res-stack weight pack ------------------------------------
__global__ __launch_bounds__(256) void k_pack(
    const float* __restrict__ il_w, const float* __restrict__ w1,
    const float* __restrict__ w2, short* __restrict__ dst)
{
    for (int idx = blockIdx.x * 256 + threadIdx.x; idx < PACK_N; idx += 512 * 256) {
        float v;
        if (idx < OFF_W1) {
            int m = idx >> 9, k = idx & 511, tap = k >> 8, ci = k & 255;
            v = il_w[(m * 256 + ci) * 2 + tap];
        } else if (idx < OFF_W2) {
            int j = idx - OFF_W1;
            int L = j >> 14, r = j & 16383;
            int m = r >> 7, k = r & 127, tap = k >> 6, ci = k & 63;
            v = w1[L * 16384 + (m * 64 + ci) * 2 + tap];
        } else {
            v = w2[idx - OFF_W2];
        }
        dst[idx] = f2bf(v);
    }
}

// ---------------- head weight pack -> d_ws ---------------------------------
__global__ __launch_bounds__(256) void k_packh(
    const float* __restrict__ w1, const float* __restrict__ w2,
    short* __restrict__ dst)
{
    int idx = blockIdx.x * 256 + threadIdx.x;     // grid 320 -> 81920
    if (idx < 81920) dst[idx] = f2bf(idx < 16384 ? w1[idx] : w2[idx - 16384]);
}

// ---------------- zero the halo flags (19*512 u32) -------------------------
__global__ __launch_bounds__(256) void k_zeroflags(unsigned* __restrict__ p) {
    int i = blockIdx.x * 256 + threadIdx.x;       // grid 38 -> 9728
    if (i < 19 * 512) p[i] = 0u;
}

// ---------------- input layer: o[b][t][64] = conv(x, d=1); publish slice0 --
__global__ __launch_bounds__(256, 4) void k_in(
    const float* __restrict__ x, const short* __restrict__ w0p,
    const float* __restrict__ bias, short* __restrict__ o,
    short* __restrict__ haloS)
{
    __shared__ short Xs[129][132];
    const int t0 = blockIdx.x * 128;
    const int b  = blockIdx.y;
    const int tid = threadIdx.x;
    const int w = tid >> 6, ln = tid & 63, tl = ln & 15, g = ln >> 4;
    const int tw = w * 32;

    f32x4 acc[4][2];
#pragma unroll
    for (int mt = 0; mt < 4; ++mt) {
        f32x4 bv = *(const f32x4*)(bias + mt * 16 + g * 4);
        acc[mt][0] = bv; acc[mt][1] = bv;
    }

    for (int c = 0; c < 2; ++c) {
        __syncthreads();
        for (int idx = tid; idx < 129 * 32; idx += 256) {
            int r = idx >> 5, c4 = (idx & 31) * 4;
            int tg = t0 - 1 + r;
            f32x4 v = (f32x4)0.0f;
            if (tg >= 0)
                v = *(const f32x4*)(x + ((size_t)b * T_LEN + tg) * INC + c * 128 + c4);
            s16x4 sv;
#pragma unroll
            for (int j = 0; j < 4; ++j) sv[j] = f2bf(v[j]);
            *(s16x4*)&Xs[r][c4] = sv;
        }
        __syncthreads();
#pragma unroll
        for (int ks = 0; ks < 8; ++ks) {
            int tap = ks >> 2;
            int ci  = (ks & 3) * 32 + g * 8;
            s16x8 bfr[2];
#pragma unroll
            for (int nf = 0; nf < 2; ++nf) {
                int row = tw + nf * 16 + tl + tap;
                s16x4 lo = *(const s16x4*)&Xs[row][ci];
                s16x4 hi = *(const s16x4*)&Xs[row][ci + 4];
                bfr[nf] = __builtin_shufflevector(lo, hi, 0, 1, 2, 3, 4, 5, 6, 7);
            }
#pragma unroll
            for (int mt = 0; mt < 4; ++mt) {
                const s16x8 a = *(const s16x8*)(
                    w0p + (size_t)(mt * 16 + tl) * 512 + tap * 256 + c * 128 + (ks & 3) * 32 + g * 8);
                acc[mt][0] = MFMA(a, bfr[0], acc[mt][0]);
                acc[mt][1] = MFMA(a, bfr[1], acc[mt][1]);
            }
        }
    }
#pragma unroll
    for (int mt = 0; mt < 4; ++mt)
#pragma unroll
        for (int nf = 0; nf < 2; ++nf) {
            int t = t0 + tw + nf * 16 + tl;
            s16x4 ov;
#pragma unroll
            for (int r = 0; r < 4; ++r) ov[r] = f2bf(acc[mt][nf][r]);
            *(s16x4*)(o + ((size_t)b * T_LEN + t) * RES + mt * 16 + g * 4) = ov;
            // publish layer-0 halo: col 255 of each 256-tile (q_0 = 1)
            if ((blockIdx.x & 1) && w == 3 && nf == 1 && tl == 15) {
                size_t hb = ((size_t)(b * 64 + (blockIdx.x >> 1)) * HALO_COLS) * 64;
                *(s16x4*)(haloS + hb + mt * 16 + g * 4) = ov;
            }
        }
}

// ---------------- fused residual stack (16 waves x 16t, per-wave poll) -----
__global__ __launch_bounds__(1024, 4) void k_fused(
    short* __restrict__ o,
    const short* __restrict__ wpk,
    const float* __restrict__ b1all, const float* __restrict__ b2all,
    short* __restrict__ skip_out,
    u64* __restrict__ halo, unsigned* __restrict__ flags)
{
    __shared__ short W1s[16384];    // [128][128] swizzled, 32 KB
    __shared__ short W2s[4096];     // [64][64]   swizzled,  8 KB
    __shared__ short Zs[256][68];   // z tile [t][ch], per-wave private rows
    const int bx = blockIdx.x;      // identity mapping: producers dispatch first
    const int by = blockIdx.y;
    const int t0 = bx * 256;
    const int tid = threadIdx.x;
    const int w = tid >> 6, ln = tid & 63, tl = ln & 15, g = ln >> 4;
    const int tw = w * 16;          // 16 waves x 16 t
    const int xm = (tl & 7) << 4;
    const size_t ob = (size_t)by * T_LEN * RES;
    const int flatblk = by * 64 + bx;

    f32x4 skip[4];
#pragma unroll
    for (int mt = 0; mt < 4; ++mt) skip[mt] = (f32x4)0.0f;

    for (int s = 0; s < NB; ++s) {
        const int dil = 1 << (s % 10);
        const int q   = (dil < 256) ? dil : 256;
        const int hoff = halo_off(s);
        const short* w1p = wpk + OFF_W1 + s * 16384;
        const short* w2p = wpk + OFF_W2 + s * 4096;
        const float* b1  = b1all + s * GATE;
        const float* b2  = b2all + s * RES;

        // ---- 1. stage weights -> LDS (shared by all 16 waves)
        for (int gi = tid; gi < 2560; gi += 1024) {
            if (gi < 2048) {
                int m = gi >> 4, c = gi & 15;
                s16x8 v = *(const s16x8*)(w1p + m * 128 + c * 8);
                *(s16x8*)((char*)W1s + ((m * 256 + c * 16) ^ ((m & 7) << 4))) = v;
            } else {
                int g2 = gi - 2048;
                int m = g2 >> 3, c = g2 & 7;
                s16x8 v = *(const s16x8*)(w2p + m * 64 + c * 8);
                *(s16x8*)((char*)W2s + ((m * 128 + c * 16) ^ ((m & 7) << 4))) = v;
            }
        }

        // ---- 2. own-region B-frag loads (center taps + interior left taps)
        const int t = t0 + tw + tl;
        s16x8 bfr[4];
#pragma unroll
        for (int ks = 0; ks < 2; ++ks) {
            int ci = ks * 32 + g * 8;
            int c = t - dil;
            s16x8 bf = (s16x8)0;
            if (c >= t0) bf = *(const s16x8*)(o + ob + (size_t)c * RES + ci);
            bfr[ks] = bf;
        }
        bfr[2] = *(const s16x8*)(o + ob + (size_t)t * RES + g * 8);
        bfr[3] = *(const s16x8*)(o + ob + (size_t)t * RES + 32 + g * 8);

        // ---- 3. barrier: staging visible + o read/write separation
        __syncthreads();

        // ---- 4. per-wave poll: only waves whose left taps cross t0
        if (s >= 1) {
            if (dil == 512) {
                if (bx >= 2 && ln == 0)
                    poll_flag(flags + (s - 1) * 512 + flatblk - 2);
            } else if (bx >= 1 && tw < dil) {
                if (ln == 0)
                    poll_flag(flags + (s - 1) * 512 + flatblk - 1);
            }
        }

        // ---- 5. boundary halo loads (u64 coherence-point reads)
#pragma unroll
        for (int ks = 0; ks < 2; ++ks) {
            int c = t - dil;
            if (c < t0 && c >= 0) {
                int ci = ks * 32 + g * 8;
                int bxp = c >> 8;
                int loc = (c & 255) - (256 - q);
                const u64* hp = halo +
                    ((size_t)(by * 64 + bxp) * HALO_COLS + hoff + loc) * 16 + (ci >> 2);
                union { u64 u[2]; s16x8 v; } un;
                un.u[0] = __hip_atomic_load(hp + 0, __ATOMIC_RELAXED, __HIP_MEMORY_SCOPE_AGENT);
                un.u[1] = __hip_atomic_load(hp + 1, __ATOMIC_RELAXED, __HIP_MEMORY_SCOPE_AGENT);
                bfr[ks] = un.v;
            }
        }

        // ---- GEMM1 (gate conv) + gating
#pragma unroll
        for (int mp = 0; mp < 4; ++mp) {
            f32x4 accA = *(const f32x4*)(b1 + mp * 16 + g * 4);
            f32x4 accG = *(const f32x4*)(b1 + 64 + mp * 16 + g * 4);
#pragma unroll
            for (int ks = 0; ks < 4; ++ks) {
                const s16x8 aA = *(const s16x8*)((const char*)W1s +
                    (((mp * 16 + tl) * 256 + ks * 64 + g * 16) ^ xm));
                const s16x8 aG = *(const s16x8*)((const char*)W1s +
                    ((((mp + 4) * 16 + tl) * 256 + ks * 64 + g * 16) ^ xm));
                accA = MFMA(aA, bfr[ks], accA);
                accG = MFMA(aG, bfr[ks], accG);
            }
            float z0 = fast_tanh(accA[0]) * fast_sigmoid(accG[0]);
            float z1 = fast_tanh(accA[1]) * fast_sigmoid(accG[1]);
            float z2 = fast_tanh(accA[2]) * fast_sigmoid(accG[2]);
            float z3 = fast_tanh(accA[3]) * fast_sigmoid(accG[3]);
            unsigned* zp = (unsigned*)&Zs[tw + tl][mp * 16 + g * 4];
            zp[0] = cvt_pk_bf16(z0, z1);
            zp[1] = cvt_pk_bf16(z2, z3);
        }

        // ---- GEMM2 (1x1): same-wave LDS rows -> no barrier
        f32x4 acc2[4];
#pragma unroll
        for (int mt = 0; mt < 4; ++mt)
            acc2[mt] = *(const f32x4*)(b2 + mt * 16 + g * 4);
#pragma unroll
        for (int ks = 0; ks < 2; ++ks) {
            s16x4 lo = *(const s16x4*)&Zs[tw + tl][ks * 32 + g * 8];
            s16x4 hi = *(const s16x4*)&Zs[tw + tl][ks * 32 + g * 8 + 4];
            s16x8 bz = __builtin_shufflevector(lo, hi, 0, 1, 2, 3, 4, 5, 6, 7);
#pragma unroll
            for (int mt = 0; mt < 4; ++mt) {
                const s16x8 a2 = *(const s16x8*)((const char*)W2s +
                    (((mt * 16 + tl) * 128 + ks * 64 + g * 16) ^ xm));
                acc2[mt] = MFMA(a2, bz, acc2[mt]);
            }
        }

        // ---- epilogue: skip += s; o += s in place; publish next halo (u64)
        const int dn  = (s < NB - 1) ? (1 << ((s + 1) % 10)) : 0;
        const int qn  = (dn < 256) ? dn : 256;
        const int hoffn = (s < NB - 1) ? halo_off(s + 1) : 0;
        const int t_local = tw + tl;
#pragma unroll
        for (int mt = 0; mt < 4; ++mt) {
#pragma unroll
            for (int r = 0; r < 4; ++r) skip[mt][r] += acc2[mt][r];
            if (s < NB - 1) {
                size_t base = ob + (size_t)(t0 + t_local) * RES + mt * 16 + g * 4;
                s16x4 ov = *(const s16x4*)(o + base);
                float f0 = bf2f(ov[0]) + acc2[mt][0];
                float f1 = bf2f(ov[1]) + acc2[mt][1];
                float f2 = bf2f(ov[2]) + acc2[mt][2];
                float f3 = bf2f(ov[3]) + acc2[mt][3];
                union { unsigned u[2]; s16x4 v; u64 uu; } un;
                un.u[0] = cvt_pk_bf16(f0, f1);
                un.u[1] = cvt_pk_bf16(f2, f3);
                *(s16x4*)(o + base) = un.v;
                if (t_local >= 256 - qn) {
                    int loc = t_local - (256 - qn);
                    u64* hp = halo +
                        ((size_t)flatblk * HALO_COLS + hoffn + loc) * 16 + mt * 4 + g;
                    __hip_atomic_store(hp, un.uu, __ATOMIC_RELAXED,
                                       __HIP_MEMORY_SCOPE_AGENT);
                }
            }
        }

        if (s < NB - 1) {
            asm volatile("s_waitcnt vmcnt(0)" ::: "memory");  // publish done
            __syncthreads();              // all waves drained
            if (tid == 0)
                __hip_atomic_store(flags + s * 512 + flatblk, 1u,
                                   __ATOMIC_RELAXED, __HIP_MEMORY_SCOPE_AGENT);
        }
    }

    // write skip (bf16) to d_ws — own tile only
    {
        int t = t0 + tw + tl;
#pragma unroll
        for (int mt = 0; mt < 4; ++mt) {
            unsigned* sp = (unsigned*)(skip_out + ob + (size_t)t * RES + mt * 16 + g * 4);
            sp[0] = cvt_pk_bf16(skip[mt][0], skip[mt][1]);
            sp[1] = cvt_pk_bf16(skip[mt][2], skip[mt][3]);
        }
    }
}

// ---------------- output head (reads d_ws only) ----------------------------
__global__ __launch_bounds__(256, 4) void k_head(
    const short* __restrict__ skip,
    const short* __restrict__ w1p, const short* __restrict__ w2p,
    const float* __restrict__ b1h, const float* __restrict__ b2h,
    float* __restrict__ out)
{
    __shared__ short T1[64][260];
    const int t0 = blockIdx.x * 64;
    const int b  = blockIdx.y;
    const int tid = threadIdx.x;
    const int w = tid >> 6, ln = tid & 63, tl = ln & 15, g = ln >> 4;
    const int m0 = w * 64;

    f32x4 acc1[4][4];
#pragma unroll
    for (int mt = 0; mt < 4; ++mt) {
        f32x4 bv = *(const f32x4*)(b1h + m0 + mt * 16 + g * 4);
#pragma unroll
        for (int nf = 0; nf < 4; ++nf) acc1[mt][nf] = bv;
    }
#pragma unroll
    for (int ks = 0; ks < 2; ++ks) {
        s16x8 bs[4];
#pragma unroll
        for (int nf = 0; nf < 4; ++nf) {
            int t = t0 + nf * 16 + tl;
            s16x8 sv = *(const s16x8*)(skip + ((size_t)b * T_LEN + t) * RES + ks * 32 + g * 8);
            s16x8 v;
#pragma unroll
            for (int j = 0; j < 8; ++j)
                v[j] = (short)(((unsigned short)sv[j] & 0x8000u) ? 0 : sv[j]);  // relu(bf16)
            bs[nf] = v;
        }
#pragma unroll
        for (int mt = 0; mt < 4; ++mt) {
            const s16x8 a = *(const s16x8*)(w1p + (size_t)(m0 + mt * 16 + tl) * 64 + ks * 32 + g * 8);
#pragma unroll
            for (int nf = 0; nf < 4; ++nf) acc1[mt][nf] = MFMA(a, bs[nf], acc1[mt][nf]);
        }
    }
#pragma unroll
    for (int mt = 0; mt < 4; ++mt)
#pragma unroll
        for (int nf = 0; nf < 4; ++nf) {
            int tloc = nf * 16 + tl;
            s16x4 zv;
#pragma unroll
            for (int r = 0; r < 4; ++r) zv[r] = f2bf(fmaxf(acc1[mt][nf][r], 0.0f));
            *(s16x4*)&T1[tloc][m0 + mt * 16 + g * 4] = zv;
        }
    __syncthreads();

    f32x4 acc2[4][4];
#pragma unroll
    for (int mt = 0; mt < 4; ++mt) {
        f32x4 bv = *(const f32x4*)(b2h + m0 + mt * 16 + g * 4);
#pragma unroll
        for (int nf = 0; nf < 4; ++nf) acc2[mt][nf] = bv;
    }
#pragma unroll
    for (int ks = 0; ks < 8; ++ks) {
        s16x8 bz[4];
#pragma unroll
        for (int nf = 0; nf < 4; ++nf) {
            s16x4 lo = *(const s16x4*)&T1[nf * 16 + tl][ks * 32 + g * 8];
            s16x4 hi = *(const s16x4*)&T1[nf * 16 + tl][ks * 32 + g * 8 + 4];
            bz[nf] = __builtin_shufflevector(lo, hi, 0, 1, 2, 3, 4, 5, 6, 7);
        }
#pragma unroll
        for (int mt = 0; mt < 4; ++mt) {
            const s16x8 a = *(const s16x8*)(w2p + (size_t)(m0 + mt * 16 + tl) * 256 + ks * 32 + g * 8);
#pragma unroll
            for (int nf = 0; nf < 4; ++nf) acc2[mt][nf] = MFMA(a, bz[nf], acc2[mt][nf]);
        }
    }
#pragma unroll
    for (int mt = 0; mt < 4; ++mt)
#pragma unroll
        for (int nf = 0; nf < 4; ++nf) {
            int t = t0 + nf * 16 + tl;
#pragma unroll
            for (int r = 0; r < 4; ++r) {
                int ch = m0 + mt * 16 + g * 4 + r;
                out[((size_t)b * OUTC + ch) * T_LEN + t] = acc2[mt][nf][r];
            }
        }
}

extern "C" void kernel_launch(void* const* d_in, const int* in_sizes, int n_in,
                              void* d_out, int out_size, void* d_ws, size_t ws_size,
                              hipStream_t stream)
{
    const float* x     = (const float*)d_in[0];
    const float* il_w  = (const float*)d_in[1];
    const float* il_b  = (const float*)d_in[2];
    const float* rb_w1 = (const float*)d_in[3];
    const float* rb_b1 = (const float*)d_in[4];
    const float* rb_w2 = (const float*)d_in[5];
    const float* rb_b2 = (const float*)d_in[6];
    const float* ol_w1 = (const float*)d_in[7];
    const float* ol_b1 = (const float*)d_in[8];
    const float* ol_w2 = (const float*)d_in[9];
    const float* ol_b2 = (const float*)d_in[10];

    const size_t planeS = (size_t)B_SZ * T_LEN * RES;    // 8,388,608 shorts
    char*  outc = (char*)d_out;
    short* o    = (short*)outc;                          // [0, 16.78 MB) in-place o
    u64*   halo = (u64*)(outc + (17u << 20));            // 100.5 MB halo mailboxes
    short* wpk  = (short*)(outc + (120u << 20));         // packed res weights
    float* out  = (float*)d_out;

    short*    skipw = (short*)d_ws;                      // [0, 16.78 MB) bf16 skip
    short*    hw    = skipw + planeS;                    // +160 KB head weights
    unsigned* flags = (unsigned*)(hw + 81920);           // 19*512 u32

    k_pack<<<dim3(512), dim3(256), 0, stream>>>(il_w, rb_w1, rb_w2, wpk);
    k_packh<<<dim3(320), dim3(256), 0, stream>>>(ol_w1, ol_w2, hw);
    k_zeroflags<<<dim3(38), dim3(256), 0, stream>>>(flags);
    k_in<<<dim3(T_LEN / 128, B_SZ), dim3(256), 0, stream>>>(x, wpk + OFF_W0, il_b, o,
                                                            (short*)halo);

    k_fused<<<dim3(T_LEN / 256, B_SZ), dim3(1024), 0, stream>>>(
        o, wpk, rb_b1, rb_b2, skipw, halo, flags);

    k_head<<<dim3(T_LEN / 64, B_SZ), dim3(256), 0, stream>>>(
        skipw, hw, hw + 16384, ol_b1, ol_b2, out);
}

// Round 19
// 507.236 us; speedup vs baseline: 1.2054x; 1.0286x over previous
//
#include <hip/hip_runtime.h>

// WaveNet B=8 T=16384 RES=64 GATE=128 IN=256 OUT=256, 20 blocks, K=2.
// Fused 20-layer stack, flag-based neighbor sync, in-place o (L2-hot),
// halo mailboxes via agent-scope relaxed atomics (r9-r18-proven).
// R19 delta vs r18 (490us, 47.6% occ, no spill): VALU-floor trim.
//   Lockstep phases make per-layer time ~= sum of pipe times; VALU (27.6%)
//   is the largest reducible term, dominated by gating. New gating:
//   tanh(a)*sig(g) = (e^2a - 1) * rcp((e^2a + 1)*(1 + e^-g)) — ONE rcp
//   (quarter-rate) instead of two, ~12 vs ~15 ops/elem. Also removed the
//   redundant explicit vmcnt(0) (syncthreads already drains).
//   Numerics shift ~1ulp fp32 pre-round -> absmax ~unchanged.
// d_out: o[0,16.8MB) | haloBuf @17MiB (100.5MB) | wpk @120MiB.
// d_ws : skip_bf16[0,16.8MB) | head weights bf16 | flags (19x512 u32).
// k_head reads ONLY d_ws -> no race with its full-d_out write (r2 lesson).

#define NB    20
#define RES   64
#define GATE  128
#define INC   256
#define OUTC  256
#define B_SZ  8
#define T_LEN 16384
#define HALO_COLS 1534     // sum of per-layer published columns

typedef short s16x4 __attribute__((ext_vector_type(4)));
typedef short s16x8 __attribute__((ext_vector_type(8)));
typedef float f32x4 __attribute__((ext_vector_type(4)));
typedef unsigned long long u64;

#define MFMA(a, b, c) __builtin_amdgcn_mfma_f32_16x16x32_bf16((a), (b), (c), 0, 0, 0)

// packed res-stack weight offsets (shorts) inside wpk
#define OFF_W0   0         // il_w   [64][512]      k = tap*256+ci
#define OFF_W1   32768     // rb_w1  [20][128][128] k = tap*64+ci
#define OFF_W2   360448    // rb_w2  [20][64][64]
#define PACK_N   442368

__device__ __forceinline__ short f2bf(float f) {
    union { float f; unsigned u; } v; v.f = f;
    unsigned r = v.u + 0x7FFFu + ((v.u >> 16) & 1u);
    return (short)(r >> 16);
}
__device__ __forceinline__ float bf2f(short s) {
    union { unsigned u; float f; } v;
    v.u = ((unsigned)(unsigned short)s) << 16;
    return v.f;
}
__device__ __forceinline__ unsigned cvt_pk_bf16(float lo, float hi) {
    unsigned r;
    asm("v_cvt_pk_bf16_f32 %0, %1, %2" : "=v"(r) : "v"(lo), "v"(hi));
    return r;
}
__device__ __forceinline__ float rcp_fast(float x) {
    float r; asm("v_rcp_f32 %0, %1" : "=v"(r) : "v"(x)); return r;
}
// z = tanh(a) * sigmoid(g) with a single rcp:
//   (e^2a - 1) * rcp((e^2a + 1) * (1 + e^-g))
__device__ __forceinline__ float gate_z(float a, float g) {
    a = fminf(fmaxf(a, -15.0f), 15.0f);
    float ea = __expf(2.0f * a);
    float eg = __expf(-g);
    return (ea - 1.0f) * rcp_fast((ea + 1.0f) * (1.0f + eg));
}
// legacy pair for k_in-free paths (unused) kept out; head uses no gating.
// halo slice s holds input halo for layer s: rightmost q_s=min(dil_s,256)
// cols of o_s per block. off(s) = sum_{j<s} q_j.
__device__ __forceinline__ int halo_off(int s) {
    int r = 0;
    if (s >= 10) { r = 767; s -= 10; }
    return r + ((s <= 8) ? ((1 << s) - 1) : 511);
}
__device__ __forceinline__ void poll_flag(unsigned* p) {
    long guard = 0;
    while (__hip_atomic_load(p, __ATOMIC_RELAXED, __HIP_MEMORY_SCOPE_AGENT) == 0u) {
        __builtin_amdgcn_s_sleep(1);
        if (++guard > 20000000L) break;   // anti-hang insurance
    }
}

// ---------------- res-stack weight pack ------------------------------------
__global__ __launch_bounds__(256) void k_pack(
    const float* __restrict__ il_w, const float* __restrict__ w1,
    const float* __restrict__ w2, short* __restrict__ dst)
{
    for (int idx = blockIdx.x * 256 + threadIdx.x; idx < PACK_N; idx += 512 * 256) {
        float v;
        if (idx < OFF_W1) {
            int m = idx >> 9, k = idx & 511, tap = k >> 8, ci = k & 255;
            v = il_w[(m * 256 + ci) * 2 + tap];
        } else if (idx < OFF_W2) {
            int j = idx - OFF_W1;
            int L = j >> 14, r = j & 16383;
            int m = r >> 7, k = r & 127, tap = k >> 6, ci = k & 63;
            v = w1[L * 16384 + (m * 64 + ci) * 2 + tap];
        } else {
            v = w2[idx - OFF_W2];
        }
        dst[idx] = f2bf(v);
    }
}

// ---------------- head weight pack -> d_ws ---------------------------------
__global__ __launch_bounds__(256) void k_packh(
    const float* __restrict__ w1, const float* __restrict__ w2,
    short* __restrict__ dst)
{
    int idx = blockIdx.x * 256 + threadIdx.x;     // grid 320 -> 81920
    if (idx < 81920) dst[idx] = f2bf(idx < 16384 ? w1[idx] : w2[idx - 16384]);
}

// ---------------- zero the halo flags (19*512 u32) -------------------------
__global__ __launch_bounds__(256) void k_zeroflags(unsigned* __restrict__ p) {
    int i = blockIdx.x * 256 + threadIdx.x;       // grid 38 -> 9728
    if (i < 19 * 512) p[i] = 0u;
}

// ---------------- input layer: o[b][t][64] = conv(x, d=1); publish slice0 --
__global__ __launch_bounds__(256, 4) void k_in(
    const float* __restrict__ x, const short* __restrict__ w0p,
    const float* __restrict__ bias, short* __restrict__ o,
    short* __restrict__ haloS)
{
    __shared__ short Xs[129][132];
    const int t0 = blockIdx.x * 128;
    const int b  = blockIdx.y;
    const int tid = threadIdx.x;
    const int w = tid >> 6, ln = tid & 63, tl = ln & 15, g = ln >> 4;
    const int tw = w * 32;

    f32x4 acc[4][2];
#pragma unroll
    for (int mt = 0; mt < 4; ++mt) {
        f32x4 bv = *(const f32x4*)(bias + mt * 16 + g * 4);
        acc[mt][0] = bv; acc[mt][1] = bv;
    }

    for (int c = 0; c < 2; ++c) {
        __syncthreads();
        for (int idx = tid; idx < 129 * 32; idx += 256) {
            int r = idx >> 5, c4 = (idx & 31) * 4;
            int tg = t0 - 1 + r;
            f32x4 v = (f32x4)0.0f;
            if (tg >= 0)
                v = *(const f32x4*)(x + ((size_t)b * T_LEN + tg) * INC + c * 128 + c4);
            s16x4 sv;
#pragma unroll
            for (int j = 0; j < 4; ++j) sv[j] = f2bf(v[j]);
            *(s16x4*)&Xs[r][c4] = sv;
        }
        __syncthreads();
#pragma unroll
        for (int ks = 0; ks < 8; ++ks) {
            int tap = ks >> 2;
            int ci  = (ks & 3) * 32 + g * 8;
            s16x8 bfr[2];
#pragma unroll
            for (int nf = 0; nf < 2; ++nf) {
                int row = tw + nf * 16 + tl + tap;
                s16x4 lo = *(const s16x4*)&Xs[row][ci];
                s16x4 hi = *(const s16x4*)&Xs[row][ci + 4];
                bfr[nf] = __builtin_shufflevector(lo, hi, 0, 1, 2, 3, 4, 5, 6, 7);
            }
#pragma unroll
            for (int mt = 0; mt < 4; ++mt) {
                const s16x8 a = *(const s16x8*)(
                    w0p + (size_t)(mt * 16 + tl) * 512 + tap * 256 + c * 128 + (ks & 3) * 32 + g * 8);
                acc[mt][0] = MFMA(a, bfr[0], acc[mt][0]);
                acc[mt][1] = MFMA(a, bfr[1], acc[mt][1]);
            }
        }
    }
#pragma unroll
    for (int mt = 0; mt < 4; ++mt)
#pragma unroll
        for (int nf = 0; nf < 2; ++nf) {
            int t = t0 + tw + nf * 16 + tl;
            s16x4 ov;
#pragma unroll
            for (int r = 0; r < 4; ++r) ov[r] = f2bf(acc[mt][nf][r]);
            *(s16x4*)(o + ((size_t)b * T_LEN + t) * RES + mt * 16 + g * 4) = ov;
            // publish layer-0 halo: col 255 of each 256-tile (q_0 = 1)
            if ((blockIdx.x & 1) && w == 3 && nf == 1 && tl == 15) {
                size_t hb = ((size_t)(b * 64 + (blockIdx.x >> 1)) * HALO_COLS) * 64;
                *(s16x4*)(haloS + hb + mt * 16 + g * 4) = ov;
            }
        }
}

// ---------------- fused residual stack (16 waves x 16t, per-wave poll) -----
__global__ __launch_bounds__(1024, 4) void k_fused(
    short* __restrict__ o,
    const short* __restrict__ wpk,
    const float* __restrict__ b1all, const float* __restrict__ b2all,
    short* __restrict__ skip_out,
    u64* __restrict__ halo, unsigned* __restrict__ flags)
{
    __shared__ short W1s[16384];    // [128][128] swizzled, 32 KB
    __shared__ short W2s[4096];     // [64][64]   swizzled,  8 KB
    __shared__ short Zs[256][68];   // z tile [t][ch], per-wave private rows
    const int bx = blockIdx.x;      // identity mapping: producers dispatch first
    const int by = blockIdx.y;
    const int t0 = bx * 256;
    const int tid = threadIdx.x;
    const int w = tid >> 6, ln = tid & 63, tl = ln & 15, g = ln >> 4;
    const int tw = w * 16;          // 16 waves x 16 t
    const int xm = (tl & 7) << 4;
    const size_t ob = (size_t)by * T_LEN * RES;
    const int flatblk = by * 64 + bx;

    f32x4 skip[4];
#pragma unroll
    for (int mt = 0; mt < 4; ++mt) skip[mt] = (f32x4)0.0f;

    for (int s = 0; s < NB; ++s) {
        const int dil = 1 << (s % 10);
        const int q   = (dil < 256) ? dil : 256;
        const int hoff = halo_off(s);
        const short* w1p = wpk + OFF_W1 + s * 16384;
        const short* w2p = wpk + OFF_W2 + s * 4096;
        const float* b1  = b1all + s * GATE;
        const float* b2  = b2all + s * RES;

        // ---- 1. stage weights -> LDS (shared by all 16 waves)
        for (int gi = tid; gi < 2560; gi += 1024) {
            if (gi < 2048) {
                int m = gi >> 4, c = gi & 15;
                s16x8 v = *(const s16x8*)(w1p + m * 128 + c * 8);
                *(s16x8*)((char*)W1s + ((m * 256 + c * 16) ^ ((m & 7) << 4))) = v;
            } else {
                int g2 = gi - 2048;
                int m = g2 >> 3, c = g2 & 7;
                s16x8 v = *(const s16x8*)(w2p + m * 64 + c * 8);
                *(s16x8*)((char*)W2s + ((m * 128 + c * 16) ^ ((m & 7) << 4))) = v;
            }
        }

        // ---- 2. own-region B-frag loads (center taps + interior left taps)
        const int t = t0 + tw + tl;
        s16x8 bfr[4];
#pragma unroll
        for (int ks = 0; ks < 2; ++ks) {
            int ci = ks * 32 + g * 8;
            int c = t - dil;
            s16x8 bf = (s16x8)0;
            if (c >= t0) bf = *(const s16x8*)(o + ob + (size_t)c * RES + ci);
            bfr[ks] = bf;
        }
        bfr[2] = *(const s16x8*)(o + ob + (size_t)t * RES + g * 8);
        bfr[3] = *(const s16x8*)(o + ob + (size_t)t * RES + 32 + g * 8);

        // ---- 3. barrier: staging visible + o read/write separation
        __syncthreads();

        // ---- 4. per-wave poll: only waves whose left taps cross t0
        if (s >= 1) {
            if (dil == 512) {
                if (bx >= 2 && ln == 0)
                    poll_flag(flags + (s - 1) * 512 + flatblk - 2);
            } else if (bx >= 1 && tw < dil) {
                if (ln == 0)
                    poll_flag(flags + (s - 1) * 512 + flatblk - 1);
            }
        }

        // ---- 5. boundary halo loads (u64 coherence-point reads)
#pragma unroll
        for (int ks = 0; ks < 2; ++ks) {
            int c = t - dil;
            if (c < t0 && c >= 0) {
                int ci = ks * 32 + g * 8;
                int bxp = c >> 8;
                int loc = (c & 255) - (256 - q);
                const u64* hp = halo +
                    ((size_t)(by * 64 + bxp) * HALO_COLS + hoff + loc) * 16 + (ci >> 2);
                union { u64 u[2]; s16x8 v; } un;
                un.u[0] = __hip_atomic_load(hp + 0, __ATOMIC_RELAXED, __HIP_MEMORY_SCOPE_AGENT);
                un.u[1] = __hip_atomic_load(hp + 1, __ATOMIC_RELAXED, __HIP_MEMORY_SCOPE_AGENT);
                bfr[ks] = un.v;
            }
        }

        // ---- GEMM1 (gate conv) + gating (merged-rcp)
#pragma unroll
        for (int mp = 0; mp < 4; ++mp) {
            f32x4 accA = *(const f32x4*)(b1 + mp * 16 + g * 4);
            f32x4 accG = *(const f32x4*)(b1 + 64 + mp * 16 + g * 4);
#pragma unroll
            for (int ks = 0; ks < 4; ++ks) {
                const s16x8 aA = *(const s16x8*)((const char*)W1s +
                    (((mp * 16 + tl) * 256 + ks * 64 + g * 16) ^ xm));
                const s16x8 aG = *(const s16x8*)((const char*)W1s +
                    ((((mp + 4) * 16 + tl) * 256 + ks * 64 + g * 16) ^ xm));
                accA = MFMA(aA, bfr[ks], accA);
                accG = MFMA(aG, bfr[ks], accG);
            }
            float z0 = gate_z(accA[0], accG[0]);
            float z1 = gate_z(accA[1], accG[1]);
            float z2 = gate_z(accA[2], accG[2]);
            float z3 = gate_z(accA[3], accG[3]);
            unsigned* zp = (unsigned*)&Zs[tw + tl][mp * 16 + g * 4];
            zp[0] = cvt_pk_bf16(z0, z1);
            zp[1] = cvt_pk_bf16(z2, z3);
        }

        // ---- GEMM2 (1x1): same-wave LDS rows -> no barrier
        f32x4 acc2[4];
#pragma unroll
        for (int mt = 0; mt < 4; ++mt)
            acc2[mt] = *(const f32x4*)(b2 + mt * 16 + g * 4);
#pragma unroll
        for (int ks = 0; ks < 2; ++ks) {
            s16x4 lo = *(const s16x4*)&Zs[tw + tl][ks * 32 + g * 8];
            s16x4 hi = *(const s16x4*)&Zs[tw + tl][ks * 32 + g * 8 + 4];
            s16x8 bz = __builtin_shufflevector(lo, hi, 0, 1, 2, 3, 4, 5, 6, 7);
#pragma unroll
            for (int mt = 0; mt < 4; ++mt) {
                const s16x8 a2 = *(const s16x8*)((const char*)W2s +
                    (((mt * 16 + tl) * 128 + ks * 64 + g * 16) ^ xm));
                acc2[mt] = MFMA(a2, bz, acc2[mt]);
            }
        }

        // ---- epilogue: skip += s; o += s in place; publish next halo (u64)
        const int dn  = (s < NB - 1) ? (1 << ((s + 1) % 10)) : 0;
        const int qn  = (dn < 256) ? dn : 256;
        const int hoffn = (s < NB - 1) ? halo_off(s + 1) : 0;
        const int t_local = tw + tl;
#pragma unroll
        for (int mt = 0; mt < 4; ++mt) {
#pragma unroll
            for (int r = 0; r < 4; ++r) skip[mt][r] += acc2[mt][r];
            if (s < NB - 1) {
                size_t base = ob + (size_t)(t0 + t_local) * RES + mt * 16 + g * 4;
                s16x4 ov = *(const s16x4*)(o + base);
                float f0 = bf2f(ov[0]) + acc2[mt][0];
                float f1 = bf2f(ov[1]) + acc2[mt][1];
                float f2 = bf2f(ov[2]) + acc2[mt][2];
                float f3 = bf2f(ov[3]) + acc2[mt][3];
                union { unsigned u[2]; s16x4 v; u64 uu; } un;
                un.u[0] = cvt_pk_bf16(f0, f1);
                un.u[1] = cvt_pk_bf16(f2, f3);
                *(s16x4*)(o + base) = un.v;
                if (t_local >= 256 - qn) {
                    int loc = t_local - (256 - qn);
                    u64* hp = halo +
                        ((size_t)flatblk * HALO_COLS + hoffn + loc) * 16 + mt * 4 + g;
                    __hip_atomic_store(hp, un.uu, __ATOMIC_RELAXED,
                                       __HIP_MEMORY_SCOPE_AGENT);
                }
            }
        }

        if (s < NB - 1) {
            __syncthreads();              // drains all vmem (compiler waitcnt)
            if (tid == 0)
                __hip_atomic_store(flags + s * 512 + flatblk, 1u,
                                   __ATOMIC_RELAXED, __HIP_MEMORY_SCOPE_AGENT);
        }
    }

    // write skip (bf16) to d_ws — own tile only
    {
        int t = t0 + tw + tl;
#pragma unroll
        for (int mt = 0; mt < 4; ++mt) {
            unsigned* sp = (unsigned*)(skip_out + ob + (size_t)t * RES + mt * 16 + g * 4);
            sp[0] = cvt_pk_bf16(skip[mt][0], skip[mt][1]);
            sp[1] = cvt_pk_bf16(skip[mt][2], skip[mt][3]);
        }
    }
}

// ---------------- output head (reads d_ws only) ----------------------------
__global__ __launch_bounds__(256, 4) void k_head(
    const short* __restrict__ skip,
    const short* __restrict__ w1p, const short* __restrict__ w2p,
    const float* __restrict__ b1h, const float* __restrict__ b2h,
    float* __restrict__ out)
{
    __shared__ short T1[64][260];
    const int t0 = blockIdx.x * 64;
    const int b  = blockIdx.y;
    const int tid = threadIdx.x;
    const int w = tid >> 6, ln = tid & 63, tl = ln & 15, g = ln >> 4;
    const int m0 = w * 64;

    f32x4 acc1[4][4];
#pragma unroll
    for (int mt = 0; mt < 4; ++mt) {
        f32x4 bv = *(const f32x4*)(b1h + m0 + mt * 16 + g * 4);
#pragma unroll
        for (int nf = 0; nf < 4; ++nf) acc1[mt][nf] = bv;
    }
#pragma unroll
    for (int ks = 0; ks < 2; ++ks) {
        s16x8 bs[4];
#pragma unroll
        for (int nf = 0; nf < 4; ++nf) {
            int t = t0 + nf * 16 + tl;
            s16x8 sv = *(const s16x8*)(skip + ((size_t)b * T_LEN + t) * RES + ks * 32 + g * 8);
            s16x8 v;
#pragma unroll
            for (int j = 0; j < 8; ++j)
                v[j] = (short)(((unsigned short)sv[j] & 0x8000u) ? 0 : sv[j]);  // relu(bf16)
            bs[nf] = v;
        }
#pragma unroll
        for (int mt = 0; mt < 4; ++mt) {
            const s16x8 a = *(const s16x8*)(w1p + (size_t)(m0 + mt * 16 + tl) * 64 + ks * 32 + g * 8);
#pragma unroll
            for (int nf = 0; nf < 4; ++nf) acc1[mt][nf] = MFMA(a, bs[nf], acc1[mt][nf]);
        }
    }
#pragma unroll
    for (int mt = 0; mt < 4; ++mt)
#pragma unroll
        for (int nf = 0; nf < 4; ++nf) {
            int tloc = nf * 16 + tl;
            s16x4 zv;
#pragma unroll
            for (int r = 0; r < 4; ++r) zv[r] = f2bf(fmaxf(acc1[mt][nf][r], 0.0f));
            *(s16x4*)&T1[tloc][m0 + mt * 16 + g * 4] = zv;
        }
    __syncthreads();

    f32x4 acc2[4][4];
#pragma unroll
    for (int mt = 0; mt < 4; ++mt) {
        f32x4 bv = *(const f32x4*)(b2h + m0 + mt * 16 + g * 4);
#pragma unroll
        for (int nf = 0; nf < 4; ++nf) acc2[mt][nf] = bv;
    }
#pragma unroll
    for (int ks = 0; ks < 8; ++ks) {
        s16x8 bz[4];
#pragma unroll
        for (int nf = 0; nf < 4; ++nf) {
            s16x4 lo = *(const s16x4*)&T1[nf * 16 + tl][ks * 32 + g * 8];
            s16x4 hi = *(const s16x4*)&T1[nf * 16 + tl][ks * 32 + g * 8 + 4];
            bz[nf] = __builtin_shufflevector(lo, hi, 0, 1, 2, 3, 4, 5, 6, 7);
        }
#pragma unroll
        for (int mt = 0; mt < 4; ++mt) {
            const s16x8 a = *(const s16x8*)(w2p + (size_t)(m0 + mt * 16 + tl) * 256 + ks * 32 + g * 8);
#pragma unroll
            for (int nf = 0; nf < 4; ++nf) acc2[mt][nf] = MFMA(a, bz[nf], acc2[mt][nf]);
        }
    }
#pragma unroll
    for (int mt = 0; mt < 4; ++mt)
#pragma unroll
        for (int nf = 0; nf < 4; ++nf) {
            int t = t0 + nf * 16 + tl;
#pragma unroll
            for (int r = 0; r < 4; ++r) {
                int ch = m0 + mt * 16 + g * 4 + r;
                out[((size_t)b * OUTC + ch) * T_LEN + t] = acc2[mt][nf][r];
            }
        }
}

extern "C" void kernel_launch(void* const* d_in, const int* in_sizes, int n_in,
                              void* d_out, int out_size, void* d_ws, size_t ws_size,
                              hipStream_t stream)
{
    const float* x     = (const float*)d_in[0];
    const float* il_w  = (const float*)d_in[1];
    const float* il_b  = (const float*)d_in[2];
    const float* rb_w1 = (const float*)d_in[3];
    const float* rb_b1 = (const float*)d_in[4];
    const float* rb_w2 = (const float*)d_in[5];
    const float* rb_b2 = (const float*)d_in[6];
    const float* ol_w1 = (const float*)d_in[7];
    const float* ol_b1 = (const float*)d_in[8];
    const float* ol_w2 = (const float*)d_in[9];
    const float* ol_b2 = (const float*)d_in[10];

    const size_t planeS = (size_t)B_SZ * T_LEN * RES;    // 8,388,608 shorts
    char*  outc = (char*)d_out;
    short* o    = (short*)outc;                          // [0, 16.78 MB) in-place o
    u64*   halo = (u64*)(outc + (17u << 20));            // 100.5 MB halo mailboxes
    short* wpk  = (short*)(outc + (120u << 20));         // packed res weights
    float* out  = (float*)d_out;

    short*    skipw = (short*)d_ws;                      // [0, 16.78 MB) bf16 skip
    short*    hw    = skipw + planeS;                    // +160 KB head weights
    unsigned* flags = (unsigned*)(hw + 81920);           // 19*512 u32

    k_pack<<<dim3(512), dim3(256), 0, stream>>>(il_w, rb_w1, rb_w2, wpk);
    k_packh<<<dim3(320), dim3(256), 0, stream>>>(ol_w1, ol_w2, hw);
    k_zeroflags<<<dim3(38), dim3(256), 0, stream>>>(flags);
    k_in<<<dim3(T_LEN / 128, B_SZ), dim3(256), 0, stream>>>(x, wpk + OFF_W0, il_b, o,
                                                            (short*)halo);

    k_fused<<<dim3(T_LEN / 256, B_SZ), dim3(1024), 0, stream>>>(
        o, wpk, rb_b1, rb_b2, skipw, halo, flags);

    k_head<<<dim3(T_LEN / 64, B_SZ), dim3(256), 0, stream>>>(
        skipw, hw, hw + 16384, ol_b1, ol_b2, out);
}